// Round 3
// baseline (462.807 us; speedup 1.0000x reference)
//
#include <hip/hip_runtime.h>
#include <cmath>

// CausalSelfAttention fused pipeline, MI355X/gfx950.
// R12: attn = exact R9 structure (paired 512 uniform blocks, lb(256,2),
// k_lds+vt_lds staged, ones-column rowsum, alpha-skip) + three deltas:
//  (1) T14 async-STAGE split: next tile's K/V global loads issued into regs
//      during current tile's compute; ds_write after the barrier. Staging
//      latency hides under compute instead of between barriers.
//  (2) XCD stream swizzle: 1-D grid, stream=(D&7) -> (b,kvh); round-robin
//      D->XCD gives each XCD one 1MB KV stream (L2-resident).
//  (3) p_lds pad 72 (R11 counters proved conflict-identical to 136).
// Plus: five f32->f16 converts fused into one launch. GEMMs unchanged.

#define S_LEN 2048
#define DMODEL 2048
#define NH 16
#define NKV 4
#define HD 128

#define NEG_SENT -1.0e30f
#define QK_SCALE 0.08838834764831845f  // 1/sqrt(128), folded into Q

typedef _Float16 f16x8 __attribute__((ext_vector_type(8)));
typedef float f32x4 __attribute__((ext_vector_type(4)));

static __device__ __forceinline__ short f2h(float f) {
  _Float16 h = (_Float16)f;
  return *(short*)&h;
}
static __device__ __forceinline__ float h2f(short s) {
  _Float16 h = *(_Float16*)&s;
  return (float)h;
}

// async global->LDS, 16B per lane; lds dst = wave-uniform base + lane*16.
static __device__ __forceinline__ void stage16(const short* g, short* ldsbase) {
  __builtin_amdgcn_global_load_lds(
      (const __attribute__((address_space(1))) void*)g,
      (__attribute__((address_space(3))) void*)ldsbase, 16, 0, 0);
}

// ---------------------------------------------------------------------------
// Fused fp32 -> fp16 convert for all five tensors in one launch.
// Segment sizes in float4 units (all multiples of 256, so each 256-thread
// block maps to exactly one segment -> wave-uniform branch):
//   x: 2097152 | q_w: 1048576 | k_w: 262144 | v_w: 262144 | out_w: 1048576
// Total 4718592 float4 -> grid 18432.
// ---------------------------------------------------------------------------
__global__ __launch_bounds__(256) void f32_to_f16_all(
    const float* __restrict__ s0, const float* __restrict__ s1,
    const float* __restrict__ s2, const float* __restrict__ s3,
    const float* __restrict__ s4, short* __restrict__ d0,
    short* __restrict__ d1, short* __restrict__ d2, short* __restrict__ d3,
    short* __restrict__ d4) {
  int u = blockIdx.x * 256 + threadIdx.x;  // float4 index
  const float* src;
  short* dst;
  int off;
  if (u < 2097152) {
    src = s0; dst = d0; off = u;
  } else if (u < 3145728) {
    src = s1; dst = d1; off = u - 2097152;
  } else if (u < 3407872) {
    src = s2; dst = d2; off = u - 3145728;
  } else if (u < 3670016) {
    src = s3; dst = d3; off = u - 3407872;
  } else {
    src = s4; dst = d4; off = u - 3670016;
  }
  float4 v = *reinterpret_cast<const float4*>(src + (size_t)off * 4);
  short4 o;
  o.x = f2h(v.x); o.y = f2h(v.y); o.z = f2h(v.z); o.w = f2h(v.w);
  *reinterpret_cast<short4*>(dst + (size_t)off * 4) = o;
}

// ---------------------------------------------------------------------------
// GEMM core: C[M,N] = A[M,K] @ W[N,K]^T, fp16 in, fp32 accum.
// 128x128 tile, BK=64. Staging via global_load_lds_dwordx4: wave w stages
// rows {w*8 + i*32 + lane/8}, cols (lane&7)*8 — LDS is unpadded [128][64]
// so lane l lands at base + l*16B exactly (required by the instruction).
// ---------------------------------------------------------------------------
template <bool F32OUT>
static __device__ __forceinline__ void gemm_core(const short* __restrict__ A,
                                                 const short* __restrict__ W,
                                                 void* __restrict__ Cv,
                                                 int N, int K, int bm, int bn) {
  __shared__ __align__(16) short As[128][64];
  __shared__ __align__(16) short Ws[128][64];
  const int tid = threadIdx.x;
  const int wave = tid >> 6, lane = tid & 63;
  const int quad = lane >> 4, l16 = lane & 15;
  const int wm = (wave >> 1) * 64, wn = (wave & 1) * 64;

  f32x4 acc[4][4];
#pragma unroll
  for (int i = 0; i < 4; i++)
#pragma unroll
    for (int j = 0; j < 4; j++) acc[i][j] = f32x4{0.f, 0.f, 0.f, 0.f};

  const int srow = wave * 8 + (lane >> 3);  // staging row (this lane)
  const int scol = (lane & 7) * 8;          // staging col

  for (int k0 = 0; k0 < K; k0 += 64) {
    __syncthreads();  // prior compute done before overwrite
#pragma unroll
    for (int i = 0; i < 4; i++) {
      stage16(A + (size_t)(bm + srow + i * 32) * K + k0 + scol,
              &As[wave * 8 + i * 32][0]);
      stage16(W + (size_t)(bn + srow + i * 32) * K + k0 + scol,
              &Ws[wave * 8 + i * 32][0]);
    }
    __syncthreads();  // staging visible (vmcnt drained by compiler)
#pragma unroll
    for (int kk = 0; kk < 64; kk += 32) {
      f16x8 af[4], bfr[4];
#pragma unroll
      for (int mi = 0; mi < 4; mi++)
        af[mi] = *reinterpret_cast<const f16x8*>(&As[wm + mi * 16 + l16][kk + quad * 8]);
#pragma unroll
      for (int ni = 0; ni < 4; ni++)
        bfr[ni] = *reinterpret_cast<const f16x8*>(&Ws[wn + ni * 16 + l16][kk + quad * 8]);
#pragma unroll
      for (int mi = 0; mi < 4; mi++)
#pragma unroll
        for (int ni = 0; ni < 4; ni++)
          acc[mi][ni] = __builtin_amdgcn_mfma_f32_16x16x32_f16(af[mi], bfr[ni], acc[mi][ni], 0, 0, 0);
    }
  }
  // C/D layout: row = quad*4 + r, col = l16
#pragma unroll
  for (int mi = 0; mi < 4; mi++)
#pragma unroll
    for (int ni = 0; ni < 4; ni++) {
      int gr = bm + wm + mi * 16 + quad * 4;
      int gc = bn + wn + ni * 16 + l16;
#pragma unroll
      for (int r = 0; r < 4; r++) {
        if (F32OUT)
          ((float*)Cv)[(size_t)(gr + r) * N + gc] = acc[mi][ni][r];
        else
          ((short*)Cv)[(size_t)(gr + r) * N + gc] = f2h(acc[mi][ni][r]);
      }
    }
}

template <bool F32OUT>
__global__ __launch_bounds__(256) void gemm_bt(const short* __restrict__ A,
                                               const short* __restrict__ W,
                                               void* __restrict__ Cv,
                                               int N, int K) {
  gemm_core<F32OUT>(A, W, Cv, N, K, blockIdx.x * 128, blockIdx.y * 128);
}

// K and V projections fused: blockIdx.z selects (W, C). Grid (32,4,2) = 256.
__global__ __launch_bounds__(256) void gemm_kv(const short* __restrict__ A,
                                               const short* __restrict__ W0,
                                               const short* __restrict__ W1,
                                               short* __restrict__ C0,
                                               short* __restrict__ C1,
                                               int N, int K) {
  const short* W = blockIdx.z ? W1 : W0;
  short* C = blockIdx.z ? C1 : C0;
  gemm_core<false>(A, W, (void*)C, N, K, blockIdx.x * 128, blockIdx.y * 128);
}

// ---------------------------------------------------------------------------
// Per-(token,head) RMSNorm + partial RoPE + optional gain, relayout to
// [b][head][s][128]. mode: 1=norm+rope(k), 2=norm+rope+gain*qk_scale(q).
// ---------------------------------------------------------------------------
__global__ __launch_bounds__(256) void postproc(const short* __restrict__ src,
                                                short* __restrict__ dst,
                                                const float* __restrict__ gain,
                                                int n_heads, int mode) {
  int gw = blockIdx.x * 4 + (threadIdx.x >> 6);
  int lane = threadIdx.x & 63;
  int head = gw % n_heads;
  int token = gw / n_heads;
  int s = token & (S_LEN - 1);
  int b = token >> 11;
  const short* sp = src + (size_t)token * (n_heads * HD) + head * HD;
  float v0 = h2f(sp[lane]);
  float v1 = h2f(sp[lane + 64]);
  float ss = v0 * v0 + v1 * v1;
#pragma unroll
  for (int off = 1; off < 64; off <<= 1) ss += __shfl_xor(ss, off, 64);
  float sc = rsqrtf(ss * (1.0f / 128.0f) + 1.1920929e-07f);
  v0 *= sc;
  v1 *= sc;
  int i = lane & 31;
  float inv = powf(10000.0f, -((float)(2 * i) * (1.0f / 64.0f)));
  float f = (float)s * inv;
  float cs, sn;
  sincosf(f, &sn, &cs);
  float partner = __shfl_xor(v0, 32, 64);
  v0 = (lane < 32) ? (v0 * cs + partner * sn) : (v0 * cs - partner * sn);
  if (mode == 2) {
    float g = gain[head] * QK_SCALE;  // fold 1/sqrt(d) into Q
    v0 *= g;
    v1 *= g;
  }
  short* dp = dst + ((size_t)(b * n_heads + head) * S_LEN + s) * HD;
  dp[lane] = f2h(v0);
  dp[lane + 64] = f2h(v1);
}

// ---------------------------------------------------------------------------
// Tiled transpose: vraw[token][512] -> vT[b][kv][dim128][seq2048].
// ---------------------------------------------------------------------------
__global__ __launch_bounds__(256) void v_transpose(const short* __restrict__ src,
                                                   short* __restrict__ dst) {
  __shared__ __align__(16) short t[64][72];
  const int tid = threadIdx.x;
  const int s0 = blockIdx.x * 64;
  const int d0 = blockIdx.y * 64;
#pragma unroll
  for (int i = 0; i < 2; i++) {
    int r = (tid >> 3) + i * 32;
    int c = (tid & 7) * 8;
    *reinterpret_cast<int4*>(&t[r][c]) =
        *reinterpret_cast<const int4*>(src + (size_t)(s0 + r) * 512 + d0 + c);
  }
  __syncthreads();
  const int b = s0 >> 11;
  const int sbase = s0 & (S_LEN - 1);
#pragma unroll
  for (int i = 0; i < 2; i++) {
    int dr = (tid >> 3) + i * 32;
    int sc8 = (tid & 7) * 8;
    int d = d0 + dr;
    int kv = d >> 7, dw = d & 127;
    short4 lo, hi;
    lo.x = t[sc8 + 0][dr]; lo.y = t[sc8 + 1][dr];
    lo.z = t[sc8 + 2][dr]; lo.w = t[sc8 + 3][dr];
    hi.x = t[sc8 + 4][dr]; hi.y = t[sc8 + 5][dr];
    hi.z = t[sc8 + 6][dr]; hi.w = t[sc8 + 7][dr];
    short* dp = dst + (((size_t)(b * NKV + kv) * HD + dw) * S_LEN) + sbase + sc8;
    *reinterpret_cast<short4*>(dp) = lo;
    *reinterpret_cast<short4*>(dp + 4) = hi;
  }
}

// ---------------------------------------------------------------------------
// Flash-style causal attention, R12 = R9 structure + T14 prefetch + XCD
// stream swizzle. Block = 4 waves; wave = 16 queries; pair-in-block over
// BQ=64 sub-blocks (512 uniform blocks, 2/CU, lb(256,2)).
// 1-D grid, D = blockIdx.x:
//   strm = D&7  -> (b = strm>>2, kvh = strm&3); with round-robin D->XCD
//   assignment, each XCD sees exactly one (b,kvh) KV stream (1MB, fits L2).
//   t = D>>3; pj = t>>2 (0..15); h = kvh*4 + (t&3).
// Per tile: [barrier] ds_write regs->LDS [barrier] issue next tile's global
// loads into regs (T14: latency hides under compute) then compute.
// ---------------------------------------------------------------------------
__global__ __launch_bounds__(256, 2) void attn_fwd(const short* __restrict__ qb,
                                                   const short* __restrict__ kb,
                                                   const short* __restrict__ vT,
                                                   short* __restrict__ out) {
  __shared__ __align__(16) short k_lds[64][136];
  __shared__ __align__(16) short vt_lds[144][72];
  __shared__ __align__(16) short p_lds[4][16][72];

  const int tid = threadIdx.x, wave = tid >> 6, lane = tid & 63;
  const int quad = lane >> 4, l16 = lane & 15;
  const int D = blockIdx.x;
  const int strm = D & 7;      // KV stream -> XCD (round-robin assumption)
  const int t = D >> 3;        // 0..63
  const int pj = t >> 2;       // 0..15
  const int b = strm >> 2;     // 0..1
  const int kvh = strm & 3;    // 0..3
  const int h = kvh * 4 + (t & 3);

  const short* kptr = kb + ((size_t)(b * NKV + kvh) * S_LEN) * HD;
  const short* vtp  = vT + ((size_t)(b * NKV + kvh) * HD) * S_LEN;

  const int kr = (tid >> 4), kc = (tid & 15) * 8;
  const int vr = (tid >> 3), vc = (tid & 7) * 8;

  // ones-column tile (rows 128..143) for the rowsum-via-MFMA trick
  {
    int r = 128 + (tid >> 4);
    int c = (tid & 15) * 4;
    short val = (r == 128) ? (short)0x3C00 : (short)0;
    short4 v4 = {val, val, val, val};
    *reinterpret_cast<short4*>(&vt_lds[r][c]) = v4;
  }

  for (int pass = 0; pass < 2; pass++) {
    const int qsub = pass ? (31 - pj) : pj;
    const int q0 = qsub * 64 + wave * 16;
    const short* qptr = qb + ((size_t)(b * NH + h) * S_LEN + q0) * HD;

    f16x8 qf[4];
#pragma unroll
    for (int st = 0; st < 4; st++)
      qf[st] = *reinterpret_cast<const f16x8*>(
          qptr + (size_t)l16 * HD + st * 32 + quad * 8);

    f32x4 o[9];
#pragma unroll
    for (int i = 0; i < 9; i++) o[i] = f32x4{0.f, 0.f, 0.f, 0.f};
    float m_i[4] = {NEG_SENT, NEG_SENT, NEG_SENT, NEG_SENT};

    const int ktiles = qsub + 1;

    // T14 prologue: tile 0 of this pass into registers.
    int4 gk[4], gv[4];
#pragma unroll
    for (int i = 0; i < 4; i++)
      gk[i] = *reinterpret_cast<const int4*>(kptr + (size_t)(kr + i * 16) * HD + kc);
#pragma unroll
    for (int i = 0; i < 4; i++)
      gv[i] = *reinterpret_cast<const int4*>(vtp + (size_t)(vr + i * 32) * S_LEN + vc);

    for (int kt = 0; kt < ktiles; kt++) {
      const int kbase = kt * 64;
      __syncthreads();  // prior tile's LDS reads done before overwrite
#pragma unroll
      for (int i = 0; i < 4; i++)
        *reinterpret_cast<int4*>(&k_lds[kr + i * 16][kc]) = gk[i];
#pragma unroll
      for (int i = 0; i < 4; i++)
        *reinterpret_cast<int4*>(&vt_lds[vr + i * 32][vc]) = gv[i];
      __syncthreads();  // staging visible (also covers ones-init on iter 0)

      // T14: issue NEXT tile's global loads now; they complete under the
      // compute below (WAR on gk/gv is scoreboarded after the ds_writes).
      if (kt + 1 < ktiles) {
        const int nb = kbase + 64;
#pragma unroll
        for (int i = 0; i < 4; i++)
          gk[i] = *reinterpret_cast<const int4*>(kptr + (size_t)(nb + kr + i * 16) * HD + kc);
#pragma unroll
        for (int i = 0; i < 4; i++)
          gv[i] = *reinterpret_cast<const int4*>(vtp + (size_t)(vr + i * 32) * S_LEN + nb + vc);
      }

      f32x4 sc[4];
#pragma unroll
      for (int ct = 0; ct < 4; ct++) sc[ct] = f32x4{0.f, 0.f, 0.f, 0.f};
#pragma unroll
      for (int ct = 0; ct < 4; ct++) {
#pragma unroll
        for (int st = 0; st < 4; st++) {
          f16x8 kf = *reinterpret_cast<const f16x8*>(&k_lds[ct * 16 + l16][st * 32 + quad * 8]);
          sc[ct] = __builtin_amdgcn_mfma_f32_16x16x32_f16(qf[st], kf, sc[ct], 0, 0, 0);
        }
      }

      if (kbase + 63 > q0) {
#pragma unroll
        for (int ct = 0; ct < 4; ct++)
#pragma unroll
          for (int r = 0; r < 4; r++) {
            int qrow = q0 + quad * 4 + r;
            int col = kbase + ct * 16 + l16;
            sc[ct][r] = (col <= qrow) ? sc[ct][r] : NEG_SENT;
          }
      }

      float cand[4];
#pragma unroll
      for (int r = 0; r < 4; r++)
        cand[r] = fmaxf(fmaxf(sc[0][r], sc[1][r]), fmaxf(sc[2][r], sc[3][r]));
#pragma unroll
      for (int off = 1; off < 16; off <<= 1)
#pragma unroll
        for (int r = 0; r < 4; r++)
          cand[r] = fmaxf(cand[r], __shfl_xor(cand[r], off, 64));

      bool ch = (cand[0] > m_i[0]) | (cand[1] > m_i[1]) |
                (cand[2] > m_i[2]) | (cand[3] > m_i[3]);
      if (__any(ch)) {
        float alpha[4];
#pragma unroll
        for (int r = 0; r < 4; r++) {
          float mn = fmaxf(m_i[r], cand[r]);
          alpha[r] = __expf(m_i[r] - mn);
          m_i[r] = mn;
        }
#pragma unroll
        for (int nt = 0; nt < 9; nt++)
#pragma unroll
          for (int r = 0; r < 4; r++) o[nt][r] *= alpha[r];
      }

#pragma unroll
      for (int ct = 0; ct < 4; ct++)
#pragma unroll
        for (int r = 0; r < 4; r++) {
          float p = __expf(sc[ct][r] - m_i[r]);
          p_lds[wave][quad * 4 + r][ct * 16 + l16] = f2h(p);
        }

      f16x8 pf0 = *reinterpret_cast<const f16x8*>(&p_lds[wave][l16][quad * 8]);
      f16x8 pf1 = *reinterpret_cast<const f16x8*>(&p_lds[wave][l16][32 + quad * 8]);
#pragma unroll
      for (int nt = 0; nt < 9; nt++) {
        f16x8 vf0 = *reinterpret_cast<const f16x8*>(&vt_lds[nt * 16 + l16][quad * 8]);
        f16x8 vf1 = *reinterpret_cast<const f16x8*>(&vt_lds[nt * 16 + l16][32 + quad * 8]);
        o[nt] = __builtin_amdgcn_mfma_f32_16x16x32_f16(pf0, vf0, o[nt], 0, 0, 0);
        o[nt] = __builtin_amdgcn_mfma_f32_16x16x32_f16(pf1, vf1, o[nt], 0, 0, 0);
      }
    }

    float inv_l[4];
#pragma unroll
    for (int r = 0; r < 4; r++) {
      float l = __shfl(o[8][r], lane & 48, 64);
      inv_l[r] = 1.0f / fmaxf(l, 1e-20f);
    }
#pragma unroll
    for (int nt = 0; nt < 8; nt++)
#pragma unroll
      for (int r = 0; r < 4; r++) {
        int srow = q0 + quad * 4 + r;
        int dcol = nt * 16 + l16;
        out[((size_t)(b * S_LEN + srow)) * DMODEL + h * HD + dcol] =
            f2h(o[nt][r] * inv_l[r]);
      }
  }
}

extern "C" void kernel_launch(void* const* d_in, const int* in_sizes, int n_in,
                              void* d_out, int out_size, void* d_ws, size_t ws_size,
                              hipStream_t stream) {
  const float* x      = (const float*)d_in[0];
  const float* q_w    = (const float*)d_in[1];
  const float* k_w    = (const float*)d_in[2];
  const float* v_w    = (const float*)d_in[3];
  const float* out_w  = (const float*)d_in[4];
  const float* q_gain = (const float*)d_in[5];
  float* out = (float*)d_out;

  const int BS = 2 * S_LEN;  // 4096 tokens
  short* xb   = (short*)d_ws;                    // 8M  (16MB)
  short* wqb  = xb   + (size_t)8 * 1024 * 1024;  // 4M
  short* wkb  = wqb  + (size_t)4 * 1024 * 1024;  // 1M
  short* wvb  = wkb  + (size_t)1 * 1024 * 1024;  // 1M
  short* wob  = wvb  + (size_t)1 * 1024 * 1024;  // 4M
  short* qraw = wob  + (size_t)4 * 1024 * 1024;  // 8M
  short* kraw = qraw + (size_t)8 * 1024 * 1024;  // 2M
  short* vraw = kraw + (size_t)2 * 1024 * 1024;  // 2M (token-major V)
  short* qbuf = vraw + (size_t)2 * 1024 * 1024;  // 8M
  short* kbuf = qbuf + (size_t)8 * 1024 * 1024;  // 2M
  short* vT   = kbuf + (size_t)2 * 1024 * 1024;  // 2M ([b][kv][dim][seq])
  short* attn = qraw;                            // alias

  dim3 blk(256);
  // one fused convert launch: 4718592 float4 / 256 = 18432 blocks
  f32_to_f16_all<<<18432, blk, 0, stream>>>(x, q_w, k_w, v_w, out_w,
                                            xb, wqb, wkb, wvb, wob);

  gemm_bt<false><<<dim3(32, 16), blk, 0, stream>>>(xb, wqb, qraw, 2048, 2048);
  gemm_kv<<<dim3(32, 4, 2), blk, 0, stream>>>(xb, wkb, wvb, kraw, vraw, 512, 2048);

  postproc<<<dim3((BS * NH) / 4), blk, 0, stream>>>(qraw, qbuf, q_gain, NH, 2);
  postproc<<<dim3((BS * NKV) / 4), blk, 0, stream>>>(kraw, kbuf, q_gain, NKV, 1);
  v_transpose<<<dim3(BS / 64, 8), blk, 0, stream>>>(vraw, vT);

  attn_fwd<<<dim3(512), blk, 0, stream>>>(qbuf, kbuf, vT, attn);

  gemm_bt<true><<<dim3(32, 16), blk, 0, stream>>>(attn, wob, out, 2048, 2048);
}

// Round 4
// 372.377 us; speedup vs baseline: 1.2428x; 1.2428x over previous
//
#include <hip/hip_runtime.h>
#include <cmath>

// CausalSelfAttention fused pipeline, MI355X/gfx950.
// R13: attn = EXACT R9 inner structure (in-loop int4 staging -> LDS, no
// register prefetch: R12's reg-prefetch arrays spilled to scratch, +316MB
// of WRITE traffic) + two counter-verified deltas kept from R12:
//   - XCD stream swizzle (1-D grid, strm=D&7 -> (b,kvh)): FETCH 37->20.5MB
//   - p_lds pad 72 (conflict-identical to 136, R11 counters)
// GEMM side: Q/K/V projections fused into ONE 768-block launch (was 512+256;
// the 256-block gemm_kv ran at 1 block/CU, latency-exposed).

#define S_LEN 2048
#define DMODEL 2048
#define NH 16
#define NKV 4
#define HD 128

#define NEG_SENT -1.0e30f
#define QK_SCALE 0.08838834764831845f  // 1/sqrt(128), folded into Q

typedef _Float16 f16x8 __attribute__((ext_vector_type(8)));
typedef float f32x4 __attribute__((ext_vector_type(4)));

static __device__ __forceinline__ short f2h(float f) {
  _Float16 h = (_Float16)f;
  return *(short*)&h;
}
static __device__ __forceinline__ float h2f(short s) {
  _Float16 h = *(_Float16*)&s;
  return (float)h;
}

// async global->LDS, 16B per lane; lds dst = wave-uniform base + lane*16.
static __device__ __forceinline__ void stage16(const short* g, short* ldsbase) {
  __builtin_amdgcn_global_load_lds(
      (const __attribute__((address_space(1))) void*)g,
      (__attribute__((address_space(3))) void*)ldsbase, 16, 0, 0);
}

// ---------------------------------------------------------------------------
// Fused fp32 -> fp16 convert for all five tensors in one launch.
// Segment sizes in float4 units (all multiples of 256 -> block-uniform
// branch): x 2097152 | q_w 1048576 | k_w 262144 | v_w 262144 | out_w 1048576
// ---------------------------------------------------------------------------
__global__ __launch_bounds__(256) void f32_to_f16_all(
    const float* __restrict__ s0, const float* __restrict__ s1,
    const float* __restrict__ s2, const float* __restrict__ s3,
    const float* __restrict__ s4, short* __restrict__ d0,
    short* __restrict__ d1, short* __restrict__ d2, short* __restrict__ d3,
    short* __restrict__ d4) {
  int u = blockIdx.x * 256 + threadIdx.x;  // float4 index
  const float* src;
  short* dst;
  int off;
  if (u < 2097152) {
    src = s0; dst = d0; off = u;
  } else if (u < 3145728) {
    src = s1; dst = d1; off = u - 2097152;
  } else if (u < 3407872) {
    src = s2; dst = d2; off = u - 3145728;
  } else if (u < 3670016) {
    src = s3; dst = d3; off = u - 3407872;
  } else {
    src = s4; dst = d4; off = u - 3670016;
  }
  float4 v = *reinterpret_cast<const float4*>(src + (size_t)off * 4);
  short4 o;
  o.x = f2h(v.x); o.y = f2h(v.y); o.z = f2h(v.z); o.w = f2h(v.w);
  *reinterpret_cast<short4*>(dst + (size_t)off * 4) = o;
}

// ---------------------------------------------------------------------------
// GEMM core: C[M,N] = A[M,K] @ W[N,K]^T, fp16 in, fp32 accum.
// 128x128 tile, BK=64. Staging via global_load_lds_dwordx4: wave w stages
// rows {w*8 + i*32 + lane/8}, cols (lane&7)*8 — LDS is unpadded [128][64]
// so lane l lands at base + l*16B exactly (required by the instruction).
// ---------------------------------------------------------------------------
template <bool F32OUT>
static __device__ __forceinline__ void gemm_core(const short* __restrict__ A,
                                                 const short* __restrict__ W,
                                                 void* __restrict__ Cv,
                                                 int N, int K, int bm, int bn) {
  __shared__ __align__(16) short As[128][64];
  __shared__ __align__(16) short Ws[128][64];
  const int tid = threadIdx.x;
  const int wave = tid >> 6, lane = tid & 63;
  const int quad = lane >> 4, l16 = lane & 15;
  const int wm = (wave >> 1) * 64, wn = (wave & 1) * 64;

  f32x4 acc[4][4];
#pragma unroll
  for (int i = 0; i < 4; i++)
#pragma unroll
    for (int j = 0; j < 4; j++) acc[i][j] = f32x4{0.f, 0.f, 0.f, 0.f};

  const int srow = wave * 8 + (lane >> 3);  // staging row (this lane)
  const int scol = (lane & 7) * 8;          // staging col

  for (int k0 = 0; k0 < K; k0 += 64) {
    __syncthreads();  // prior compute done before overwrite
#pragma unroll
    for (int i = 0; i < 4; i++) {
      stage16(A + (size_t)(bm + srow + i * 32) * K + k0 + scol,
              &As[wave * 8 + i * 32][0]);
      stage16(W + (size_t)(bn + srow + i * 32) * K + k0 + scol,
              &Ws[wave * 8 + i * 32][0]);
    }
    __syncthreads();  // staging visible (vmcnt drained by compiler)
#pragma unroll
    for (int kk = 0; kk < 64; kk += 32) {
      f16x8 af[4], bfr[4];
#pragma unroll
      for (int mi = 0; mi < 4; mi++)
        af[mi] = *reinterpret_cast<const f16x8*>(&As[wm + mi * 16 + l16][kk + quad * 8]);
#pragma unroll
      for (int ni = 0; ni < 4; ni++)
        bfr[ni] = *reinterpret_cast<const f16x8*>(&Ws[wn + ni * 16 + l16][kk + quad * 8]);
#pragma unroll
      for (int mi = 0; mi < 4; mi++)
#pragma unroll
        for (int ni = 0; ni < 4; ni++)
          acc[mi][ni] = __builtin_amdgcn_mfma_f32_16x16x32_f16(af[mi], bfr[ni], acc[mi][ni], 0, 0, 0);
    }
  }
  // C/D layout: row = quad*4 + r, col = l16
#pragma unroll
  for (int mi = 0; mi < 4; mi++)
#pragma unroll
    for (int ni = 0; ni < 4; ni++) {
      int gr = bm + wm + mi * 16 + quad * 4;
      int gc = bn + wn + ni * 16 + l16;
#pragma unroll
      for (int r = 0; r < 4; r++) {
        if (F32OUT)
          ((float*)Cv)[(size_t)(gr + r) * N + gc] = acc[mi][ni][r];
        else
          ((short*)Cv)[(size_t)(gr + r) * N + gc] = f2h(acc[mi][ni][r]);
      }
    }
}

template <bool F32OUT>
__global__ __launch_bounds__(256) void gemm_bt(const short* __restrict__ A,
                                               const short* __restrict__ W,
                                               void* __restrict__ Cv,
                                               int N, int K) {
  gemm_core<F32OUT>(A, W, Cv, N, K, blockIdx.x * 128, blockIdx.y * 128);
}

// Q, K, V projections in ONE launch. Grid (32, 24): y<16 -> Q (N=2048),
// y in [16,20) -> K, y in [20,24) -> V (N=512). Block-uniform branch.
__global__ __launch_bounds__(256) void gemm_qkv(const short* __restrict__ A,
                                                const short* __restrict__ Wq,
                                                const short* __restrict__ Wk,
                                                const short* __restrict__ Wv,
                                                short* __restrict__ Cq,
                                                short* __restrict__ Ck,
                                                short* __restrict__ Cvp,
                                                int K) {
  const int y = blockIdx.y;
  const short* W;
  short* C;
  int N, bn;
  if (y < 16) {
    W = Wq; C = Cq; N = 2048; bn = y * 128;
  } else if (y < 20) {
    W = Wk; C = Ck; N = 512; bn = (y - 16) * 128;
  } else {
    W = Wv; C = Cvp; N = 512; bn = (y - 20) * 128;
  }
  gemm_core<false>(A, W, (void*)C, N, K, blockIdx.x * 128, bn);
}

// ---------------------------------------------------------------------------
// Per-(token,head) RMSNorm + partial RoPE + optional gain, relayout to
// [b][head][s][128]. mode: 1=norm+rope(k), 2=norm+rope+gain*qk_scale(q).
// ---------------------------------------------------------------------------
__global__ __launch_bounds__(256) void postproc(const short* __restrict__ src,
                                                short* __restrict__ dst,
                                                const float* __restrict__ gain,
                                                int n_heads, int mode) {
  int gw = blockIdx.x * 4 + (threadIdx.x >> 6);
  int lane = threadIdx.x & 63;
  int head = gw % n_heads;
  int token = gw / n_heads;
  int s = token & (S_LEN - 1);
  int b = token >> 11;
  const short* sp = src + (size_t)token * (n_heads * HD) + head * HD;
  float v0 = h2f(sp[lane]);
  float v1 = h2f(sp[lane + 64]);
  float ss = v0 * v0 + v1 * v1;
#pragma unroll
  for (int off = 1; off < 64; off <<= 1) ss += __shfl_xor(ss, off, 64);
  float sc = rsqrtf(ss * (1.0f / 128.0f) + 1.1920929e-07f);
  v0 *= sc;
  v1 *= sc;
  int i = lane & 31;
  float inv = powf(10000.0f, -((float)(2 * i) * (1.0f / 64.0f)));
  float f = (float)s * inv;
  float cs, sn;
  sincosf(f, &sn, &cs);
  float partner = __shfl_xor(v0, 32, 64);
  v0 = (lane < 32) ? (v0 * cs + partner * sn) : (v0 * cs - partner * sn);
  if (mode == 2) {
    float g = gain[head] * QK_SCALE;  // fold 1/sqrt(d) into Q
    v0 *= g;
    v1 *= g;
  }
  short* dp = dst + ((size_t)(b * n_heads + head) * S_LEN + s) * HD;
  dp[lane] = f2h(v0);
  dp[lane + 64] = f2h(v1);
}

// ---------------------------------------------------------------------------
// Tiled transpose: vraw[token][512] -> vT[b][kv][dim128][seq2048].
// ---------------------------------------------------------------------------
__global__ __launch_bounds__(256) void v_transpose(const short* __restrict__ src,
                                                   short* __restrict__ dst) {
  __shared__ __align__(16) short t[64][72];
  const int tid = threadIdx.x;
  const int s0 = blockIdx.x * 64;
  const int d0 = blockIdx.y * 64;
#pragma unroll
  for (int i = 0; i < 2; i++) {
    int r = (tid >> 3) + i * 32;
    int c = (tid & 7) * 8;
    *reinterpret_cast<int4*>(&t[r][c]) =
        *reinterpret_cast<const int4*>(src + (size_t)(s0 + r) * 512 + d0 + c);
  }
  __syncthreads();
  const int b = s0 >> 11;
  const int sbase = s0 & (S_LEN - 1);
#pragma unroll
  for (int i = 0; i < 2; i++) {
    int dr = (tid >> 3) + i * 32;
    int sc8 = (tid & 7) * 8;
    int d = d0 + dr;
    int kv = d >> 7, dw = d & 127;
    short4 lo, hi;
    lo.x = t[sc8 + 0][dr]; lo.y = t[sc8 + 1][dr];
    lo.z = t[sc8 + 2][dr]; lo.w = t[sc8 + 3][dr];
    hi.x = t[sc8 + 4][dr]; hi.y = t[sc8 + 5][dr];
    hi.z = t[sc8 + 6][dr]; hi.w = t[sc8 + 7][dr];
    short* dp = dst + (((size_t)(b * NKV + kv) * HD + dw) * S_LEN) + sbase + sc8;
    *reinterpret_cast<short4*>(dp) = lo;
    *reinterpret_cast<short4*>(dp + 4) = hi;
  }
}

// ---------------------------------------------------------------------------
// Flash-style causal attention, R13 = R9 body + XCD stream swizzle + pad-72.
// Block = 4 waves; wave = 16 queries; pair-in-block over BQ=64 sub-blocks
// (512 uniform blocks, 2/CU, lb(256,2)). In-loop staging (int4 -> LDS
// between barriers; NO register prefetch — R12 proved it spills).
// 1-D grid, D = blockIdx.x:
//   strm = D&7 -> (b = strm>>2, kvh = strm&3); round-robin D->XCD gives
//   each XCD one (b,kvh) KV stream (1MB, L2-resident; FETCH 37->20.5MB).
//   t = D>>3; pj = t>>2 (0..15); h = kvh*4 + (t&3).
// ---------------------------------------------------------------------------
__global__ __launch_bounds__(256, 2) void attn_fwd(const short* __restrict__ qb,
                                                   const short* __restrict__ kb,
                                                   const short* __restrict__ vT,
                                                   short* __restrict__ out) {
  __shared__ __align__(16) short k_lds[64][136];
  __shared__ __align__(16) short vt_lds[144][72];
  __shared__ __align__(16) short p_lds[4][16][72];

  const int tid = threadIdx.x, wave = tid >> 6, lane = tid & 63;
  const int quad = lane >> 4, l16 = lane & 15;
  const int D = blockIdx.x;
  const int strm = D & 7;      // KV stream -> XCD (round-robin assumption)
  const int t = D >> 3;        // 0..63
  const int pj = t >> 2;       // 0..15
  const int b = strm >> 2;     // 0..1
  const int kvh = strm & 3;    // 0..3
  const int h = kvh * 4 + (t & 3);

  const short* kptr = kb + ((size_t)(b * NKV + kvh) * S_LEN) * HD;
  const short* vtp  = vT + ((size_t)(b * NKV + kvh) * HD) * S_LEN;

  const int kr = (tid >> 4), kc = (tid & 15) * 8;
  const int vr = (tid >> 3), vc = (tid & 7) * 8;

  // ones-column tile (rows 128..143) for the rowsum-via-MFMA trick
  {
    int r = 128 + (tid >> 4);
    int c = (tid & 15) * 4;
    short val = (r == 128) ? (short)0x3C00 : (short)0;
    short4 v4 = {val, val, val, val};
    *reinterpret_cast<short4*>(&vt_lds[r][c]) = v4;
  }

  for (int pass = 0; pass < 2; pass++) {
    const int qsub = pass ? (31 - pj) : pj;
    const int q0 = qsub * 64 + wave * 16;
    const short* qptr = qb + ((size_t)(b * NH + h) * S_LEN + q0) * HD;

    f16x8 qf[4];
#pragma unroll
    for (int st = 0; st < 4; st++)
      qf[st] = *reinterpret_cast<const f16x8*>(
          qptr + (size_t)l16 * HD + st * 32 + quad * 8);

    f32x4 o[9];
#pragma unroll
    for (int i = 0; i < 9; i++) o[i] = f32x4{0.f, 0.f, 0.f, 0.f};
    float m_i[4] = {NEG_SENT, NEG_SENT, NEG_SENT, NEG_SENT};

    const int ktiles = qsub + 1;
    for (int kt = 0; kt < ktiles; kt++) {
      const int kbase = kt * 64;
      __syncthreads();  // prior tile's reads done before overwrite
#pragma unroll
      for (int i = 0; i < 4; i++)
        *reinterpret_cast<int4*>(&k_lds[kr + i * 16][kc]) =
            *reinterpret_cast<const int4*>(kptr + (size_t)(kbase + kr + i * 16) * HD + kc);
#pragma unroll
      for (int i = 0; i < 4; i++)
        *reinterpret_cast<int4*>(&vt_lds[vr + i * 32][vc]) =
            *reinterpret_cast<const int4*>(vtp + (size_t)(vr + i * 32) * S_LEN + kbase + vc);
      __syncthreads();  // staging visible (also covers ones-init on iter 0)

      f32x4 sc[4];
#pragma unroll
      for (int ct = 0; ct < 4; ct++) sc[ct] = f32x4{0.f, 0.f, 0.f, 0.f};
#pragma unroll
      for (int ct = 0; ct < 4; ct++) {
#pragma unroll
        for (int st = 0; st < 4; st++) {
          f16x8 kf = *reinterpret_cast<const f16x8*>(&k_lds[ct * 16 + l16][st * 32 + quad * 8]);
          sc[ct] = __builtin_amdgcn_mfma_f32_16x16x32_f16(qf[st], kf, sc[ct], 0, 0, 0);
        }
      }

      if (kbase + 63 > q0) {
#pragma unroll
        for (int ct = 0; ct < 4; ct++)
#pragma unroll
          for (int r = 0; r < 4; r++) {
            int qrow = q0 + quad * 4 + r;
            int col = kbase + ct * 16 + l16;
            sc[ct][r] = (col <= qrow) ? sc[ct][r] : NEG_SENT;
          }
      }

      float cand[4];
#pragma unroll
      for (int r = 0; r < 4; r++)
        cand[r] = fmaxf(fmaxf(sc[0][r], sc[1][r]), fmaxf(sc[2][r], sc[3][r]));
#pragma unroll
      for (int off = 1; off < 16; off <<= 1)
#pragma unroll
        for (int r = 0; r < 4; r++)
          cand[r] = fmaxf(cand[r], __shfl_xor(cand[r], off, 64));

      bool ch = (cand[0] > m_i[0]) | (cand[1] > m_i[1]) |
                (cand[2] > m_i[2]) | (cand[3] > m_i[3]);
      if (__any(ch)) {
        float alpha[4];
#pragma unroll
        for (int r = 0; r < 4; r++) {
          float mn = fmaxf(m_i[r], cand[r]);
          alpha[r] = __expf(m_i[r] - mn);
          m_i[r] = mn;
        }
#pragma unroll
        for (int nt = 0; nt < 9; nt++)
#pragma unroll
          for (int r = 0; r < 4; r++) o[nt][r] *= alpha[r];
      }

#pragma unroll
      for (int ct = 0; ct < 4; ct++)
#pragma unroll
        for (int r = 0; r < 4; r++) {
          float p = __expf(sc[ct][r] - m_i[r]);
          p_lds[wave][quad * 4 + r][ct * 16 + l16] = f2h(p);
        }

      f16x8 pf0 = *reinterpret_cast<const f16x8*>(&p_lds[wave][l16][quad * 8]);
      f16x8 pf1 = *reinterpret_cast<const f16x8*>(&p_lds[wave][l16][32 + quad * 8]);
#pragma unroll
      for (int nt = 0; nt < 9; nt++) {
        f16x8 vf0 = *reinterpret_cast<const f16x8*>(&vt_lds[nt * 16 + l16][quad * 8]);
        f16x8 vf1 = *reinterpret_cast<const f16x8*>(&vt_lds[nt * 16 + l16][32 + quad * 8]);
        o[nt] = __builtin_amdgcn_mfma_f32_16x16x32_f16(pf0, vf0, o[nt], 0, 0, 0);
        o[nt] = __builtin_amdgcn_mfma_f32_16x16x32_f16(pf1, vf1, o[nt], 0, 0, 0);
      }
    }

    float inv_l[4];
#pragma unroll
    for (int r = 0; r < 4; r++) {
      float l = __shfl(o[8][r], lane & 48, 64);
      inv_l[r] = 1.0f / fmaxf(l, 1e-20f);
    }
#pragma unroll
    for (int nt = 0; nt < 8; nt++)
#pragma unroll
      for (int r = 0; r < 4; r++) {
        int srow = q0 + quad * 4 + r;
        int dcol = nt * 16 + l16;
        out[((size_t)(b * S_LEN + srow)) * DMODEL + h * HD + dcol] =
            f2h(o[nt][r] * inv_l[r]);
      }
  }
}

extern "C" void kernel_launch(void* const* d_in, const int* in_sizes, int n_in,
                              void* d_out, int out_size, void* d_ws, size_t ws_size,
                              hipStream_t stream) {
  const float* x      = (const float*)d_in[0];
  const float* q_w    = (const float*)d_in[1];
  const float* k_w    = (const float*)d_in[2];
  const float* v_w    = (const float*)d_in[3];
  const float* out_w  = (const float*)d_in[4];
  const float* q_gain = (const float*)d_in[5];
  float* out = (float*)d_out;

  const int BS = 2 * S_LEN;  // 4096 tokens
  short* xb   = (short*)d_ws;                    // 8M  (16MB)
  short* wqb  = xb   + (size_t)8 * 1024 * 1024;  // 4M
  short* wkb  = wqb  + (size_t)4 * 1024 * 1024;  // 1M
  short* wvb  = wkb  + (size_t)1 * 1024 * 1024;  // 1M
  short* wob  = wvb  + (size_t)1 * 1024 * 1024;  // 4M
  short* qraw = wob  + (size_t)4 * 1024 * 1024;  // 8M
  short* kraw = qraw + (size_t)8 * 1024 * 1024;  // 2M
  short* vraw = kraw + (size_t)2 * 1024 * 1024;  // 2M (token-major V)
  short* qbuf = vraw + (size_t)2 * 1024 * 1024;  // 8M
  short* kbuf = qbuf + (size_t)8 * 1024 * 1024;  // 2M
  short* vT   = kbuf + (size_t)2 * 1024 * 1024;  // 2M ([b][kv][dim][seq])
  short* attn = qraw;                            // alias

  dim3 blk(256);
  // one fused convert launch: 4718592 float4 / 256 = 18432 blocks
  f32_to_f16_all<<<18432, blk, 0, stream>>>(x, q_w, k_w, v_w, out_w,
                                            xb, wqb, wkb, wvb, wob);

  // Q/K/V projections in one 768-block launch (3 blocks/CU uniform)
  gemm_qkv<<<dim3(32, 24), blk, 0, stream>>>(xb, wqb, wkb, wvb,
                                             qraw, kraw, vraw, 2048);

  postproc<<<dim3((BS * NH) / 4), blk, 0, stream>>>(qraw, qbuf, q_gain, NH, 2);
  postproc<<<dim3((BS * NKV) / 4), blk, 0, stream>>>(kraw, kbuf, q_gain, NKV, 1);
  v_transpose<<<dim3(BS / 64, 8), blk, 0, stream>>>(vraw, vT);

  attn_fwd<<<dim3(512), blk, 0, stream>>>(qbuf, kbuf, vT, attn);

  gemm_bt<true><<<dim3(32, 16), blk, 0, stream>>>(attn, wob, out, 2048, 2048);
}